// Round 1
// baseline (1334.542 us; speedup 1.0000x reference)
//
#include <hip/hip_runtime.h>
#include <stdint.h>
#include <math.h>

#define E_    16
#define NTOK  2048
#define D_    1024
#define H_    4096

typedef unsigned short ushort_t;
typedef __attribute__((ext_vector_type(8))) short short8;
typedef __attribute__((ext_vector_type(4))) float f32x4;

// float -> bf16 round-to-nearest-even (bit trick; inputs are finite)
__device__ __forceinline__ ushort_t f2bf(float f) {
    union { float f; unsigned int u; } v; v.f = f;
    unsigned int u = v.u;
    return (ushort_t)((u + 0x7FFFu + ((u >> 16) & 1u)) >> 16);
}

__device__ __forceinline__ void async_copy16(const ushort_t* g, ushort_t* l) {
    __builtin_amdgcn_global_load_lds(
        (const __attribute__((address_space(1))) void*)g,
        (__attribute__((address_space(3))) void*)l,
        16, 0, 0);
}

// ---------------- conversion kernels ----------------

// x: contiguous fp32 -> bf16, 4 elements/thread
__global__ void cvt_f32_bf16(const float* __restrict__ in, ushort_t* __restrict__ out) {
    int i = blockIdx.x * blockDim.x + threadIdx.x;
    const float4 v = *(const float4*)(in + (size_t)i * 4);
    ushort4 o;
    o.x = f2bf(v.x); o.y = f2bf(v.y); o.z = f2bf(v.z); o.w = f2bf(v.w);
    *(ushort4*)(out + (size_t)i * 4) = o;
}

// per-expert transpose + convert: in (R,C) fp32 -> out (C,R) bf16
__global__ void transpose_cvt(const float* __restrict__ in, ushort_t* __restrict__ out,
                              int R, int C) {
    __shared__ float tile[64][65];
    const int e = blockIdx.z;
    const float*  inp  = in  + (size_t)e * R * C;
    ushort_t*     outp = out + (size_t)e * R * C;
    const int c0 = blockIdx.x * 64, r0 = blockIdx.y * 64;
    const int tx = threadIdx.x & 63, ty = threadIdx.x >> 6;  // ty in 0..3
    #pragma unroll
    for (int i = 0; i < 16; ++i) {
        int r = ty * 16 + i;
        tile[r][tx] = inp[(size_t)(r0 + r) * C + c0 + tx];
    }
    __syncthreads();
    #pragma unroll
    for (int i = 0; i < 16; ++i) {
        int c = ty * 16 + i;
        outp[(size_t)(c0 + c) * R + r0 + tx] = f2bf(tile[tx][c]);
    }
}

// ---------------- GEMM (A: MxK row-major, Bt: NxK row-major, both bf16) ----------------
// 128x128 block tile, BK=64, 256 threads = 4 waves in 2x2, each wave 64x64 (4x4 of 16x16x32)

template<bool GELU, typename CT>
__global__ void gemm_bt(const ushort_t* __restrict__ A, const ushort_t* __restrict__ Bt,
                        CT* __restrict__ C, int M, int N, int K) {
    __shared__ ushort_t As[128 * 64];
    __shared__ ushort_t Bs[128 * 64];

    const int e  = blockIdx.z;
    const int bm = blockIdx.y, bn = blockIdx.x;
    const ushort_t* Ae = A  + (size_t)e * M * K + (size_t)(bm * 128) * K;
    const ushort_t* Be = Bt + (size_t)e * N * K + (size_t)(bn * 128) * K;
    CT* Ce = C + (size_t)e * M * N;

    const int tid  = threadIdx.x;
    const int wave = tid >> 6, lane = tid & 63;
    const int wm = wave & 1, wn = wave >> 1;
    const int lr = lane & 15;             // m (A) / n (B) within 16x16 tile
    const int lk = (lane >> 4) * 8;       // k sub-offset within 32-k step

    f32x4 acc[4][4];
    #pragma unroll
    for (int i = 0; i < 4; ++i)
        #pragma unroll
        for (int j = 0; j < 4; ++j)
            acc[i][j] = (f32x4)(0.0f);

    const int row_s = lane >> 3;          // 0..7: row within 8-row staging slab
    const int ch    = (lane & 7) * 8;     // element offset of 16B chunk in row

    const int KT = K >> 6;
    for (int kt = 0; kt < KT; ++kt) {
        const int k0 = kt * 64;
        #pragma unroll
        for (int t = 0; t < 4; ++t) {
            const int rb = (wave * 4 + t) * 8;   // wave-uniform slab base row
            async_copy16(Ae + (size_t)(rb + row_s) * K + k0 + ch, &As[rb * 64]);
            async_copy16(Be + (size_t)(rb + row_s) * K + k0 + ch, &Bs[rb * 64]);
        }
        __syncthreads();   // compiler drains vmcnt(0) before s_barrier

        #pragma unroll
        for (int kk = 0; kk < 2; ++kk) {
            short8 a[4], b[4];
            #pragma unroll
            for (int i = 0; i < 4; ++i)
                a[i] = *(const short8*)&As[(wm * 64 + i * 16 + lr) * 64 + kk * 32 + lk];
            #pragma unroll
            for (int j = 0; j < 4; ++j)
                b[j] = *(const short8*)&Bs[(wn * 64 + j * 16 + lr) * 64 + kk * 32 + lk];
            #pragma unroll
            for (int i = 0; i < 4; ++i)
                #pragma unroll
                for (int j = 0; j < 4; ++j)
                    acc[i][j] = __builtin_amdgcn_mfma_f32_16x16x32_bf16(
                        a[i], b[j], acc[i][j], 0, 0, 0);
        }
        __syncthreads();
    }

    // epilogue: C/D layout for 16x16: col = lane&15, row = (lane>>4)*4 + reg
    const int cr = (lane >> 4) * 4;
    const int cc = lane & 15;
    #pragma unroll
    for (int i = 0; i < 4; ++i) {
        #pragma unroll
        for (int j = 0; j < 4; ++j) {
            #pragma unroll
            for (int r = 0; r < 4; ++r) {
                const int row = bm * 128 + wm * 64 + i * 16 + cr + r;
                const int col = bn * 128 + wn * 64 + j * 16 + cc;
                float v = acc[i][j][r];
                if constexpr (GELU) {
                    v = 0.5f * v * (1.0f + erff(v * 0.70710678118654752f));
                    Ce[(size_t)row * N + col] = (CT)f2bf(v);
                } else {
                    Ce[(size_t)row * N + col] = v;
                }
            }
        }
    }
}

// ---------------- launcher ----------------

extern "C" void kernel_launch(void* const* d_in, const int* in_sizes, int n_in,
                              void* d_out, int out_size, void* d_ws, size_t ws_size,
                              hipStream_t stream) {
    const float* x  = (const float*)d_in[0];   // (E, N, D)
    const float* w1 = (const float*)d_in[1];   // (E, D, H)
    const float* w2 = (const float*)d_in[2];   // (E, H, D)
    float* out = (float*)d_out;                // (E, N, D)

    // workspace layout (bf16 buffers): x_bf | w1t | w2t | hidden  = 576 MB total
    ushort_t* xb  = (ushort_t*)d_ws;                          // E*N*D
    ushort_t* w1t = xb  + (size_t)E_ * NTOK * D_;             // E*H*D  (w1 transposed: (H,D))
    ushort_t* w2t = w1t + (size_t)E_ * D_ * H_;               // E*D*H  (w2 transposed: (D,H))
    ushort_t* hid = w2t + (size_t)E_ * H_ * D_;               // E*N*H

    // 1. convert x to bf16
    {
        const size_t n = (size_t)E_ * NTOK * D_;              // 33,554,432
        cvt_f32_bf16<<<dim3((unsigned)(n / 4 / 256)), dim3(256), 0, stream>>>(x, xb);
    }
    // 2. transpose-convert weights: w1 (D,H)->(H,D), w2 (H,D)->(D,H)
    transpose_cvt<<<dim3(H_ / 64, D_ / 64, E_), dim3(256), 0, stream>>>(w1, w1t, D_, H_);
    transpose_cvt<<<dim3(D_ / 64, H_ / 64, E_), dim3(256), 0, stream>>>(w2, w2t, H_, D_);

    // 3. GEMM1 + GELU: hid = gelu(x @ w1)   [M=2048, N=4096, K=1024]
    gemm_bt<true, ushort_t><<<dim3(H_ / 128, NTOK / 128, E_), dim3(256), 0, stream>>>(
        xb, w1t, hid, NTOK, H_, D_);

    // 4. GEMM2: out = hid @ w2              [M=2048, N=1024, K=4096]
    gemm_bt<false, float><<<dim3(D_ / 128, NTOK / 128, E_), dim3(256), 0, stream>>>(
        hid, w2t, out, NTOK, D_, H_);
}

// Round 2
// 1295.203 us; speedup vs baseline: 1.0304x; 1.0304x over previous
//
#include <hip/hip_runtime.h>
#include <stdint.h>
#include <math.h>

#define E_    16
#define NTOK  2048
#define D_    1024
#define H_    4096

typedef unsigned short ushort_t;
typedef __attribute__((ext_vector_type(8))) short short8;
typedef __attribute__((ext_vector_type(4))) float f32x4;

// float -> bf16 round-to-nearest-even (bit trick; inputs are finite)
__device__ __forceinline__ ushort_t f2bf(float f) {
    union { float f; unsigned int u; } v; v.f = f;
    unsigned int u = v.u;
    return (ushort_t)((u + 0x7FFFu + ((u >> 16) & 1u)) >> 16);
}

__device__ __forceinline__ void async_copy16(const ushort_t* g, ushort_t* l) {
    __builtin_amdgcn_global_load_lds(
        (const __attribute__((address_space(1))) void*)g,
        (__attribute__((address_space(3))) void*)l,
        16, 0, 0);
}

// ---------------- conversion kernels ----------------

// x: contiguous fp32 -> bf16, 4 elements/thread
__global__ void cvt_f32_bf16(const float* __restrict__ in, ushort_t* __restrict__ out) {
    int i = blockIdx.x * blockDim.x + threadIdx.x;
    const float4 v = *(const float4*)(in + (size_t)i * 4);
    ushort4 o;
    o.x = f2bf(v.x); o.y = f2bf(v.y); o.z = f2bf(v.z); o.w = f2bf(v.w);
    *(ushort4*)(out + (size_t)i * 4) = o;
}

// per-expert transpose + convert: in (R,C) fp32 -> out (C,R) bf16
// 64x64 tile; float4 global loads (16B/lane), ushort4 stores (8B/lane).
// LDS tile padded to 65 -> scalar f32 LDS ops are <=2-way (free).
__global__ void transpose_cvt(const float* __restrict__ in, ushort_t* __restrict__ out,
                              int R, int C) {
    __shared__ float tile[64][65];
    const int e = blockIdx.z;
    const float*  inp  = in  + (size_t)e * R * C;
    ushort_t*     outp = out + (size_t)e * R * C;
    const int c0 = blockIdx.x * 64, r0 = blockIdx.y * 64;
    const int tx = threadIdx.x & 15, ty = threadIdx.x >> 4;  // ty in 0..15
    #pragma unroll
    for (int i = 0; i < 4; ++i) {
        const int r = i * 16 + ty;
        const float4 v = *(const float4*)(inp + (size_t)(r0 + r) * C + c0 + tx * 4);
        tile[r][tx * 4 + 0] = v.x; tile[r][tx * 4 + 1] = v.y;
        tile[r][tx * 4 + 2] = v.z; tile[r][tx * 4 + 3] = v.w;
    }
    __syncthreads();
    #pragma unroll
    for (int i = 0; i < 4; ++i) {
        const int c = i * 16 + ty;                           // out-row (input col)
        ushort4 o;
        o.x = f2bf(tile[tx * 4 + 0][c]); o.y = f2bf(tile[tx * 4 + 1][c]);
        o.z = f2bf(tile[tx * 4 + 2][c]); o.w = f2bf(tile[tx * 4 + 3][c]);
        *(ushort4*)(outp + (size_t)(c0 + c) * R + r0 + tx * 4) = o;
    }
}

// ---------------- GEMM (A: MxK row-major, Bt: NxK row-major, both bf16) ----------------
// 128x128 block tile, BK=64, 256 threads = 4 waves in 2x2, each wave 64x64 (4x4 of 16x16x32)
// LDS layout XOR-swizzled in 16B chunks: row r, logical chunk c lives at phys chunk c^(r&7).
// Kills the 16-way ds_read_b128 bank conflicts of the unswizzled 128B-stride layout.

template<bool GELU, typename CT>
__global__ void gemm_bt(const ushort_t* __restrict__ A, const ushort_t* __restrict__ Bt,
                        CT* __restrict__ C, int M, int N, int K) {
    // staging: As(128x64) + Bs(128x64) = 32768 B; GELU bounce buffer: 128x130 = 33280 B
    constexpr int SMEM_USH = GELU ? (128 * 130) : (128 * 64 * 2);
    __shared__ ushort_t smem[SMEM_USH];
    ushort_t* As = smem;
    ushort_t* Bs = smem + 128 * 64;

    const int e  = blockIdx.z;
    const int bm = blockIdx.y, bn = blockIdx.x;
    const ushort_t* Ae = A  + (size_t)e * M * K + (size_t)(bm * 128) * K;
    const ushort_t* Be = Bt + (size_t)e * N * K + (size_t)(bn * 128) * K;
    CT* Ce = C + (size_t)e * M * N;

    const int tid  = threadIdx.x;
    const int wave = tid >> 6, lane = tid & 63;
    const int wm = wave & 1, wn = wave >> 1;
    const int lr = lane & 15;             // m (A) / n (B) within 16x16 tile
    const int h  = lr & 7;                // swizzle key for frag reads
    const int cq = lane >> 4;             // 0..3 : which 8-elem chunk within 32-k step

    f32x4 acc[4][4];
    #pragma unroll
    for (int i = 0; i < 4; ++i)
        #pragma unroll
        for (int j = 0; j < 4; ++j)
            acc[i][j] = (f32x4)(0.0f);

    const int row_s = lane >> 3;                      // 0..7: row within 8-row staging slab
    const int ch    = ((lane & 7) ^ row_s) * 8;       // swizzled logical chunk offset

    const int KT = K >> 6;
    for (int kt = 0; kt < KT; ++kt) {
        const int k0 = kt * 64;
        #pragma unroll
        for (int t = 0; t < 4; ++t) {
            const int rb = (wave * 4 + t) * 8;   // wave-uniform slab base row
            async_copy16(Ae + (size_t)(rb + row_s) * K + k0 + ch, &As[rb * 64]);
            async_copy16(Be + (size_t)(rb + row_s) * K + k0 + ch, &Bs[rb * 64]);
        }
        __syncthreads();

        #pragma unroll
        for (int kk = 0; kk < 2; ++kk) {
            short8 a[4], b[4];
            #pragma unroll
            for (int i = 0; i < 4; ++i)
                a[i] = *(const short8*)&As[(wm * 64 + i * 16 + lr) * 64 +
                                           (((kk * 4 + cq) ^ h) << 3)];
            #pragma unroll
            for (int j = 0; j < 4; ++j)
                b[j] = *(const short8*)&Bs[(wn * 64 + j * 16 + lr) * 64 +
                                           (((kk * 4 + cq) ^ h) << 3)];
            #pragma unroll
            for (int i = 0; i < 4; ++i)
                #pragma unroll
                for (int j = 0; j < 4; ++j)
                    acc[i][j] = __builtin_amdgcn_mfma_f32_16x16x32_bf16(
                        a[i], b[j], acc[i][j], 0, 0, 0);
        }
        __syncthreads();
    }

    // epilogue: C/D layout for 16x16: col = lane&15, row = (lane>>4)*4 + reg
    const int cr = (lane >> 4) * 4;
    const int cc = lane & 15;

    if constexpr (GELU) {
        // GELU + cvt into LDS bounce buffer (stride 130 ushorts -> 65 dwords: reads 2-way free)
        #pragma unroll
        for (int i = 0; i < 4; ++i)
            #pragma unroll
            for (int j = 0; j < 4; ++j)
                #pragma unroll
                for (int r = 0; r < 4; ++r) {
                    const int row = wm * 64 + i * 16 + cr + r;
                    const int col = wn * 64 + j * 16 + cc;
                    float v = acc[i][j][r];
                    v = 0.5f * v * (1.0f + erff(v * 0.70710678118654752f));
                    smem[row * 130 + col] = f2bf(v);
                }
        __syncthreads();
        // coalesced 16B stores: 256 threads x 8 iters x 8 ushorts = 128x128 tile
        const unsigned int* p32 = (const unsigned int*)smem;
        const int rty = tid >> 4, rtx = tid & 15;
        #pragma unroll
        for (int it = 0; it < 8; ++it) {
            const int row = it * 16 + rty;
            const int base = row * 65 + rtx * 4;          // dword index
            uint4 v;
            v.x = p32[base + 0]; v.y = p32[base + 1];
            v.z = p32[base + 2]; v.w = p32[base + 3];
            *(uint4*)(Ce + (size_t)(bm * 128 + row) * N + bn * 128 + rtx * 8) = v;
        }
    } else {
        #pragma unroll
        for (int i = 0; i < 4; ++i)
            #pragma unroll
            for (int j = 0; j < 4; ++j)
                #pragma unroll
                for (int r = 0; r < 4; ++r) {
                    const int row = bm * 128 + wm * 64 + i * 16 + cr + r;
                    const int col = bn * 128 + wn * 64 + j * 16 + cc;
                    Ce[(size_t)row * N + col] = acc[i][j][r];
                }
    }
}

// ---------------- launcher ----------------

extern "C" void kernel_launch(void* const* d_in, const int* in_sizes, int n_in,
                              void* d_out, int out_size, void* d_ws, size_t ws_size,
                              hipStream_t stream) {
    const float* x  = (const float*)d_in[0];   // (E, N, D)
    const float* w1 = (const float*)d_in[1];   // (E, D, H)
    const float* w2 = (const float*)d_in[2];   // (E, H, D)
    float* out = (float*)d_out;                // (E, N, D)

    // workspace layout (bf16 buffers): x_bf | w1t | w2t | hidden
    ushort_t* xb  = (ushort_t*)d_ws;                          // E*N*D
    ushort_t* w1t = xb  + (size_t)E_ * NTOK * D_;             // E*H*D  (w1 transposed: (H,D))
    ushort_t* w2t = w1t + (size_t)E_ * D_ * H_;               // E*D*H  (w2 transposed: (D,H))
    ushort_t* hid = w2t + (size_t)E_ * H_ * D_;               // E*N*H

    // 1. convert x to bf16
    {
        const size_t n = (size_t)E_ * NTOK * D_;
        cvt_f32_bf16<<<dim3((unsigned)(n / 4 / 256)), dim3(256), 0, stream>>>(x, xb);
    }
    // 2. transpose-convert weights: w1 (D,H)->(H,D), w2 (H,D)->(D,H)
    transpose_cvt<<<dim3(H_ / 64, D_ / 64, E_), dim3(256), 0, stream>>>(w1, w1t, D_, H_);
    transpose_cvt<<<dim3(D_ / 64, H_ / 64, E_), dim3(256), 0, stream>>>(w2, w2t, H_, D_);

    // 3. GEMM1 + GELU: hid = gelu(x @ w1)   [M=2048, N=4096, K=1024]
    gemm_bt<true, ushort_t><<<dim3(H_ / 128, NTOK / 128, E_), dim3(256), 0, stream>>>(
        xb, w1t, hid, NTOK, H_, D_);

    // 4. GEMM2: out = hid @ w2              [M=2048, N=1024, K=4096]
    gemm_bt<false, float><<<dim3(D_ / 128, NTOK / 128, E_), dim3(256), 0, stream>>>(
        hid, w2t, out, NTOK, D_, H_);
}